// Round 1
// baseline (463.798 us; speedup 1.0000x reference)
//
#include <hip/hip_runtime.h>
#include <cstdint>
#include <cstddef>

typedef __bf16 bf16x8 __attribute__((ext_vector_type(8)));
typedef float f32x4 __attribute__((ext_vector_type(4)));
typedef unsigned short u16;
typedef unsigned short u16x8 __attribute__((ext_vector_type(8)));

#define BATCH 4096
#define NE 8

__device__ __forceinline__ u16 f2bf(float f) {
  union { float f; uint32_t u; } v; v.f = f;
  uint32_t u = v.u;
  u += 0x7fffu + ((u >> 16) & 1u);   // RTNE
  return (u16)(u >> 16);
}

// A[b, e*K0 + i] = blend[b,e] * h[b,i]   (bf16 out)
__global__ void expand_a_kernel(const float* __restrict__ h,
                                const float* __restrict__ blend,
                                u16* __restrict__ A, int K0) {
  int t = blockIdx.x * blockDim.x + threadIdx.x;   // one thread per 8 elements
  int per_row = K0 >> 3;
  int b = t / per_row;
  int i0 = (t - b * per_row) << 3;
  const float4* hp = (const float4*)(h + (size_t)b * K0 + i0);
  float4 ha = hp[0], hb = hp[1];
  float hv[8] = {ha.x, ha.y, ha.z, ha.w, hb.x, hb.y, hb.z, hb.w};
  const float4* blp = (const float4*)(blend + b * NE);
  float4 b0 = blp[0], b1 = blp[1];
  float bl[8] = {b0.x, b0.y, b0.z, b0.w, b1.x, b1.y, b1.z, b1.w};
  size_t base = (size_t)b * ((size_t)NE * K0) + i0;
  #pragma unroll
  for (int e = 0; e < NE; ++e) {
    u16x8 o;
    #pragma unroll
    for (int j = 0; j < 8; ++j) o[j] = f2bf(bl[e] * hv[j]);
    *(u16x8*)(A + base + (size_t)e * K0) = o;
  }
}

// W (E, N, K0) fp32  ->  Bt (N, E*K0) bf16 : Bt[o, e*K0+i] = W[e,o,i]
__global__ void convert_w_kernel(const float* __restrict__ W,
                                 u16* __restrict__ Bt, int N, int K0) {
  int t = blockIdx.x * blockDim.x + threadIdx.x;   // one thread per 8 elements
  int per_row = K0 >> 3;
  int rid = t / per_row;                 // rid = e*N + o
  int i0 = (t - rid * per_row) << 3;
  int e = rid / N;
  int o = rid - e * N;
  const float4* wp = (const float4*)(W + (size_t)rid * K0 + i0);
  float4 wa = wp[0], wb = wp[1];
  float wv[8] = {wa.x, wa.y, wa.z, wa.w, wb.x, wb.y, wb.z, wb.w};
  u16x8 ov;
  #pragma unroll
  for (int j = 0; j < 8; ++j) ov[j] = f2bf(wv[j]);
  *(u16x8*)(Bt + (size_t)o * ((size_t)NE * K0) + (size_t)e * K0 + i0) = ov;
}

#define GL2LDS(g, l) __builtin_amdgcn_global_load_lds( \
    (__attribute__((address_space(1))) void*)(g),      \
    (__attribute__((address_space(3))) void*)(l), 16, 0, 0)

// C(M x N) = A(M x EK) @ Bt(N x EK)^T, fused bias (blend @ Bias) + optional ELU.
// BM=64, BN=128, BK=32. 256 threads = 4 waves (2x2), wave tile 32x64 (2x4 MFMA tiles).
template<bool ELU_ACT, bool SPLITK>
__global__ __launch_bounds__(256, 2)
void gemm_bt_kernel(const u16* __restrict__ A, const u16* __restrict__ Bt,
                    const float* __restrict__ blend, const float* __restrict__ Bias,
                    float* __restrict__ C, int EK, int N) {
  __shared__ __align__(16) u16 As[64 * 32];
  __shared__ __align__(16) u16 Bs[128 * 32];

  const int tid  = threadIdx.x;
  const int w    = tid >> 6, lane = tid & 63;
  const int wm   = w >> 1,   wn   = w & 1;
  const int lrow = lane & 15, quad = lane >> 4;

  const int row0 = blockIdx.x * 64;
  const int col0 = blockIdx.y * 128;

  const int klen = EK / gridDim.z;
  const int kbeg = blockIdx.z * klen;

  // global->LDS staging addresses (wave-uniform LDS base + lane*16 layout)
  const u16* gA  = A  + (size_t)(row0 + (tid >> 2)) * EK + kbeg + ((tid & 3) << 3);
  const u16* gB0 = Bt + (size_t)(col0 + (tid >> 2)) * EK + kbeg + ((tid & 3) << 3);
  const u16* gB1 = Bt + (size_t)(col0 + ((tid + 256) >> 2)) * EK + kbeg + (((tid + 256) & 3) << 3);
  u16* lA  = &As[tid * 8];
  u16* lB0 = &Bs[tid * 8];
  u16* lB1 = &Bs[(tid + 256) * 8];

  // LDS fragment read pointers (invariant over K loop)
  const u16* fA0 = &As[(wm * 32 + 0 * 16 + lrow) * 32 + quad * 8];
  const u16* fA1 = &As[(wm * 32 + 1 * 16 + lrow) * 32 + quad * 8];
  const u16* fB0 = &Bs[(wn * 64 + 0 * 16 + lrow) * 32 + quad * 8];
  const u16* fB1 = &Bs[(wn * 64 + 1 * 16 + lrow) * 32 + quad * 8];
  const u16* fB2 = &Bs[(wn * 64 + 2 * 16 + lrow) * 32 + quad * 8];
  const u16* fB3 = &Bs[(wn * 64 + 3 * 16 + lrow) * 32 + quad * 8];

  f32x4 acc[2][4];
  #pragma unroll
  for (int i = 0; i < 2; ++i)
    #pragma unroll
    for (int j = 0; j < 4; ++j) acc[i][j] = (f32x4){0.f, 0.f, 0.f, 0.f};

  const int ksteps = klen >> 5;
  for (int kt = 0; kt < ksteps; ++kt) {
    GL2LDS(gA, lA);
    GL2LDS(gB0, lB0);
    GL2LDS(gB1, lB1);
    gA += 32; gB0 += 32; gB1 += 32;
    __syncthreads();

    bf16x8 a0 = *(const bf16x8*)fA0;
    bf16x8 a1 = *(const bf16x8*)fA1;
    bf16x8 b0 = *(const bf16x8*)fB0;
    bf16x8 b1 = *(const bf16x8*)fB1;
    bf16x8 b2 = *(const bf16x8*)fB2;
    bf16x8 b3 = *(const bf16x8*)fB3;
    acc[0][0] = __builtin_amdgcn_mfma_f32_16x16x32_bf16(a0, b0, acc[0][0], 0, 0, 0);
    acc[1][0] = __builtin_amdgcn_mfma_f32_16x16x32_bf16(a1, b0, acc[1][0], 0, 0, 0);
    acc[0][1] = __builtin_amdgcn_mfma_f32_16x16x32_bf16(a0, b1, acc[0][1], 0, 0, 0);
    acc[1][1] = __builtin_amdgcn_mfma_f32_16x16x32_bf16(a1, b1, acc[1][1], 0, 0, 0);
    acc[0][2] = __builtin_amdgcn_mfma_f32_16x16x32_bf16(a0, b2, acc[0][2], 0, 0, 0);
    acc[1][2] = __builtin_amdgcn_mfma_f32_16x16x32_bf16(a1, b2, acc[1][2], 0, 0, 0);
    acc[0][3] = __builtin_amdgcn_mfma_f32_16x16x32_bf16(a0, b3, acc[0][3], 0, 0, 0);
    acc[1][3] = __builtin_amdgcn_mfma_f32_16x16x32_bf16(a1, b3, acc[1][3], 0, 0, 0);
    __syncthreads();
  }

  // Epilogue: C/D layout col = lane&15, row = quad*4 + reg (m89/m91 verified)
  float bcol[4][NE];
  #pragma unroll
  for (int nt = 0; nt < 4; ++nt) {
    int col = col0 + wn * 64 + nt * 16 + lrow;
    #pragma unroll
    for (int e = 0; e < NE; ++e) bcol[nt][e] = Bias[e * N + col];
  }
  #pragma unroll
  for (int mt = 0; mt < 2; ++mt) {
    #pragma unroll
    for (int r = 0; r < 4; ++r) {
      int row = row0 + wm * 32 + mt * 16 + quad * 4 + r;
      const float4* blp = (const float4*)(blend + row * NE);
      float4 u0 = blp[0], u1 = blp[1];
      float bl[8] = {u0.x, u0.y, u0.z, u0.w, u1.x, u1.y, u1.z, u1.w};
      #pragma unroll
      for (int nt = 0; nt < 4; ++nt) {
        int col = col0 + wn * 64 + nt * 16 + lrow;
        float v = acc[mt][nt][r];
        if (!SPLITK || blockIdx.z == 0) {
          float bias = 0.f;
          #pragma unroll
          for (int e = 0; e < NE; ++e) bias += bl[e] * bcol[nt][e];
          v += bias;
        }
        if (ELU_ACT) v = v > 0.f ? v : expm1f(v);
        if (SPLITK) atomicAdd(&C[(size_t)row * N + col], v);
        else        C[(size_t)row * N + col] = v;
      }
    }
  }
}

extern "C" void kernel_launch(void* const* d_in, const int* in_sizes, int n_in,
                              void* d_out, int out_size, void* d_ws, size_t ws_size,
                              hipStream_t stream) {
  const float* blend = (const float*)d_in[0];
  const float* x  = (const float*)d_in[1];
  const float* W0 = (const float*)d_in[2];
  const float* B0 = (const float*)d_in[3];
  const float* W1 = (const float*)d_in[4];
  const float* B1 = (const float*)d_in[5];
  const float* W2 = (const float*)d_in[6];
  const float* B2 = (const float*)d_in[7];
  float* out = (float*)d_out;

  char* ws = (char*)d_ws;
  const size_t SZ_H = (size_t)4096 * 1024 * sizeof(float);       // 16.78 MB
  float* h0  = (float*)ws;
  float* h1  = (float*)(ws + SZ_H);
  u16*  Abuf = (u16*)(ws + 2 * SZ_H);                            // up to 4096x8192 bf16 = 67.1 MB
  u16*  Btbf = (u16*)(ws + 2 * SZ_H + (size_t)4096 * 8192 * 2);  // up to 1024x8192 bf16 = 16.78 MB

  // ---- Layer 0: K0=512, EK=4096, N=1024, ELU ----
  expand_a_kernel<<<BATCH * 512 / 8 / 256, 256, 0, stream>>>(x, blend, Abuf, 512);
  convert_w_kernel<<<NE * 1024 * 512 / 8 / 256, 256, 0, stream>>>(W0, Btbf, 1024, 512);
  gemm_bt_kernel<true, false><<<dim3(64, 8, 1), 256, 0, stream>>>(Abuf, Btbf, blend, B0, h0, 4096, 1024);

  // ---- Layer 1: K0=1024, EK=8192, N=1024, ELU ----
  expand_a_kernel<<<BATCH * 1024 / 8 / 256, 256, 0, stream>>>(h0, blend, Abuf, 1024);
  convert_w_kernel<<<NE * 1024 * 1024 / 8 / 256, 256, 0, stream>>>(W1, Btbf, 1024, 1024);
  gemm_bt_kernel<true, false><<<dim3(64, 8, 1), 256, 0, stream>>>(Abuf, Btbf, blend, B1, h1, 8192, 1024);

  // ---- Layer 2: K0=1024, EK=8192, N=512, linear, split-K=2 ----
  expand_a_kernel<<<BATCH * 1024 / 8 / 256, 256, 0, stream>>>(h1, blend, Abuf, 1024);
  convert_w_kernel<<<NE * 512 * 1024 / 8 / 256, 256, 0, stream>>>(W2, Btbf, 512, 1024);
  hipMemsetAsync(out, 0, (size_t)out_size * sizeof(float), stream);
  gemm_bt_kernel<false, true><<<dim3(64, 4, 2), 256, 0, stream>>>(Abuf, Btbf, blend, B2, out, 8192, 512);
}

// Round 2
// 376.430 us; speedup vs baseline: 1.2321x; 1.2321x over previous
//
#include <hip/hip_runtime.h>
#include <cstdint>
#include <cstddef>

typedef __bf16 bf16x8 __attribute__((ext_vector_type(8)));
typedef float f32x4 __attribute__((ext_vector_type(4)));
typedef unsigned short u16;
typedef unsigned short u16x8 __attribute__((ext_vector_type(8)));

#define BATCH 4096
#define NE 8

__device__ __forceinline__ u16 f2bf(float f) {
  union { float f; uint32_t u; } v; v.f = f;
  uint32_t u = v.u;
  u += 0x7fffu + ((u >> 16) & 1u);   // RTNE
  return (u16)(u >> 16);
}

// A[b, e*K0 + i] = blend[b,e] * x[b,i]   (bf16 out) — layer-0 expand
__global__ void expand_a_kernel(const float* __restrict__ h,
                                const float* __restrict__ blend,
                                u16* __restrict__ A, int K0) {
  int t = blockIdx.x * blockDim.x + threadIdx.x;   // one thread per 8 elements
  int per_row = K0 >> 3;
  int b = t / per_row;
  int i0 = (t - b * per_row) << 3;
  const float4* hp = (const float4*)(h + (size_t)b * K0 + i0);
  float4 ha = hp[0], hb = hp[1];
  float hv[8] = {ha.x, ha.y, ha.z, ha.w, hb.x, hb.y, hb.z, hb.w};
  const float4* blp = (const float4*)(blend + b * NE);
  float4 b0 = blp[0], b1 = blp[1];
  float bl[8] = {b0.x, b0.y, b0.z, b0.w, b1.x, b1.y, b1.z, b1.w};
  size_t base = (size_t)b * ((size_t)NE * K0) + i0;
  #pragma unroll
  for (int e = 0; e < NE; ++e) {
    u16x8 o;
    #pragma unroll
    for (int j = 0; j < 8; ++j) o[j] = f2bf(bl[e] * hv[j]);
    *(u16x8*)(A + base + (size_t)e * K0) = o;
  }
}

// Fused: h = ELU(P0 + P1 + blend@Bias); A[b, e*N + i] = bf16(blend[b,e] * h[b,i])
__global__ void expand_fused_kernel(const float* __restrict__ P,
                                    const float* __restrict__ blend,
                                    const float* __restrict__ Bias,
                                    u16* __restrict__ A, int N) {
  int t = blockIdx.x * blockDim.x + threadIdx.x;
  int per_row = N >> 3;
  int b = t / per_row;
  int i0 = (t - b * per_row) << 3;
  const size_t slice = (size_t)BATCH * N;
  const float4* p0 = (const float4*)(P + (size_t)b * N + i0);
  const float4* p1 = (const float4*)(P + slice + (size_t)b * N + i0);
  float4 v0a = p0[0], v0b = p0[1], v1a = p1[0], v1b = p1[1];
  float v[8] = {v0a.x + v1a.x, v0a.y + v1a.y, v0a.z + v1a.z, v0a.w + v1a.w,
                v0b.x + v1b.x, v0b.y + v1b.y, v0b.z + v1b.z, v0b.w + v1b.w};
  const float4* blp = (const float4*)(blend + b * NE);
  float4 u0 = blp[0], u1 = blp[1];
  float bl[8] = {u0.x, u0.y, u0.z, u0.w, u1.x, u1.y, u1.z, u1.w};
  #pragma unroll
  for (int e = 0; e < NE; ++e) {
    const float4* bp = (const float4*)(Bias + (size_t)e * N + i0);
    float4 ba = bp[0], bb = bp[1];
    float bv[8] = {ba.x, ba.y, ba.z, ba.w, bb.x, bb.y, bb.z, bb.w};
    #pragma unroll
    for (int j = 0; j < 8; ++j) v[j] += bl[e] * bv[j];
  }
  #pragma unroll
  for (int j = 0; j < 8; ++j) v[j] = v[j] > 0.f ? v[j] : expm1f(v[j]);
  size_t base = (size_t)b * ((size_t)NE * N) + i0;
  #pragma unroll
  for (int e = 0; e < NE; ++e) {
    u16x8 o;
    #pragma unroll
    for (int j = 0; j < 8; ++j) o[j] = f2bf(bl[e] * v[j]);
    *(u16x8*)(A + base + (size_t)e * N) = o;
  }
}

// out[b,o] = sum_{s<4} P_s[b,o] + blend@Bias   (final layer, linear)
__global__ void final_combine_kernel(const float* __restrict__ P,
                                     const float* __restrict__ blend,
                                     const float* __restrict__ Bias,
                                     float* __restrict__ out, int N) {
  int t = blockIdx.x * blockDim.x + threadIdx.x;
  int per_row = N >> 3;
  int b = t / per_row;
  int i0 = (t - b * per_row) << 3;
  const size_t slice = (size_t)BATCH * N;
  float v[8] = {0, 0, 0, 0, 0, 0, 0, 0};
  #pragma unroll
  for (int s = 0; s < 4; ++s) {
    const float4* p = (const float4*)(P + s * slice + (size_t)b * N + i0);
    float4 pa = p[0], pb = p[1];
    float pv[8] = {pa.x, pa.y, pa.z, pa.w, pb.x, pb.y, pb.z, pb.w};
    #pragma unroll
    for (int j = 0; j < 8; ++j) v[j] += pv[j];
  }
  const float4* blp = (const float4*)(blend + b * NE);
  float4 u0 = blp[0], u1 = blp[1];
  float bl[8] = {u0.x, u0.y, u0.z, u0.w, u1.x, u1.y, u1.z, u1.w};
  #pragma unroll
  for (int e = 0; e < NE; ++e) {
    const float4* bp = (const float4*)(Bias + (size_t)e * N + i0);
    float4 ba = bp[0], bb = bp[1];
    float bv[8] = {ba.x, ba.y, ba.z, ba.w, bb.x, bb.y, bb.z, bb.w};
    #pragma unroll
    for (int j = 0; j < 8; ++j) v[j] += bl[e] * bv[j];
  }
  float4* op = (float4*)(out + (size_t)b * N + i0);
  op[0] = (float4){v[0], v[1], v[2], v[3]};
  op[1] = (float4){v[4], v[5], v[6], v[7]};
}

// W (E, N, K0) fp32  ->  Bt (N, E*K0) bf16 : Bt[o, e*K0+i] = W[e,o,i]
__global__ void convert_w_kernel(const float* __restrict__ W,
                                 u16* __restrict__ Bt, int N, int K0) {
  int t = blockIdx.x * blockDim.x + threadIdx.x;   // one thread per 8 elements
  int per_row = K0 >> 3;
  int rid = t / per_row;                 // rid = e*N + o
  int i0 = (t - rid * per_row) << 3;
  int e = rid / N;
  int o = rid - e * N;
  const float4* wp = (const float4*)(W + (size_t)rid * K0 + i0);
  float4 wa = wp[0], wb = wp[1];
  float wv[8] = {wa.x, wa.y, wa.z, wa.w, wb.x, wb.y, wb.z, wb.w};
  u16x8 ov;
  #pragma unroll
  for (int j = 0; j < 8; ++j) ov[j] = f2bf(wv[j]);
  *(u16x8*)(Bt + (size_t)o * ((size_t)NE * K0) + (size_t)e * K0 + i0) = ov;
}

#define GL2LDS(g, l) __builtin_amdgcn_global_load_lds( \
    (__attribute__((address_space(1))) void*)(g),      \
    (__attribute__((address_space(3))) void*)(l), 16, 0, 0)

// P_slice(M x N) = A(M x EK_slice) @ Bt(N x EK_slice)^T, raw fp32 partials.
// m97 structure: BM=BN=128, BK=32, 256 threads = 4 waves (2x2), wave tile 64x64,
// 16 MFMA : 8 ds_read_b128 : 4 global_load_lds per K-step.
template<int SLICES>
__global__ __launch_bounds__(256, 2)
void gemm128_kernel(const u16* __restrict__ A, const u16* __restrict__ Bt,
                    float* __restrict__ P, int EK, int N) {
  __shared__ __align__(16) u16 As[128 * 32];
  __shared__ __align__(16) u16 Bs[128 * 32];

  const int tid  = threadIdx.x;
  const int w    = tid >> 6, lane = tid & 63;
  const int wm   = w >> 1,   wn   = w & 1;
  const int lrow = lane & 15, quad = lane >> 4;

  const int row0 = blockIdx.x * 128;
  const int col0 = blockIdx.y * 128;
  const int klen = EK / SLICES;
  const int kbeg = blockIdx.z * klen;

  // staging: 512 chunks of 16B per operand; thread handles chunks tid, tid+256
  const u16* gA0 = A + (size_t)(row0 + (tid >> 2)) * EK + kbeg + ((tid & 3) << 3);
  const u16* gA1 = gA0 + (size_t)64 * EK;
  const u16* gB0 = Bt + (size_t)(col0 + (tid >> 2)) * EK + kbeg + ((tid & 3) << 3);
  const u16* gB1 = gB0 + (size_t)64 * EK;
  u16* lA0 = &As[tid * 8];
  u16* lA1 = &As[tid * 8 + 256 * 8];
  u16* lB0 = &Bs[tid * 8];
  u16* lB1 = &Bs[tid * 8 + 256 * 8];

  const u16* fA[4];
  const u16* fB[4];
  #pragma unroll
  for (int i = 0; i < 4; ++i) {
    fA[i] = &As[(wm * 64 + i * 16 + lrow) * 32 + quad * 8];
    fB[i] = &Bs[(wn * 64 + i * 16 + lrow) * 32 + quad * 8];
  }

  f32x4 acc[4][4];
  #pragma unroll
  for (int i = 0; i < 4; ++i)
    #pragma unroll
    for (int j = 0; j < 4; ++j) acc[i][j] = (f32x4){0.f, 0.f, 0.f, 0.f};

  const int ksteps = klen >> 5;
  for (int kt = 0; kt < ksteps; ++kt) {
    GL2LDS(gA0, lA0);
    GL2LDS(gA1, lA1);
    GL2LDS(gB0, lB0);
    GL2LDS(gB1, lB1);
    gA0 += 32; gA1 += 32; gB0 += 32; gB1 += 32;
    __syncthreads();

    bf16x8 af[4], bf[4];
    #pragma unroll
    for (int i = 0; i < 4; ++i) af[i] = *(const bf16x8*)fA[i];
    #pragma unroll
    for (int j = 0; j < 4; ++j) bf[j] = *(const bf16x8*)fB[j];
    #pragma unroll
    for (int i = 0; i < 4; ++i)
      #pragma unroll
      for (int j = 0; j < 4; ++j)
        acc[i][j] = __builtin_amdgcn_mfma_f32_16x16x32_bf16(af[i], bf[j], acc[i][j], 0, 0, 0);
    __syncthreads();
  }

  // C/D layout: col = lane&15, row = quad*4 + reg (m89/m91 verified)
  float* Ps = P + (size_t)blockIdx.z * ((size_t)BATCH * N);
  #pragma unroll
  for (int mt = 0; mt < 4; ++mt) {
    #pragma unroll
    for (int r = 0; r < 4; ++r) {
      int row = row0 + wm * 64 + mt * 16 + quad * 4 + r;
      #pragma unroll
      for (int nt = 0; nt < 4; ++nt) {
        int col = col0 + wn * 64 + nt * 16 + lrow;
        Ps[(size_t)row * N + col] = acc[mt][nt][r];
      }
    }
  }
}

extern "C" void kernel_launch(void* const* d_in, const int* in_sizes, int n_in,
                              void* d_out, int out_size, void* d_ws, size_t ws_size,
                              hipStream_t stream) {
  const float* blend = (const float*)d_in[0];
  const float* x  = (const float*)d_in[1];
  const float* W0 = (const float*)d_in[2];
  const float* B0 = (const float*)d_in[3];
  const float* W1 = (const float*)d_in[4];
  const float* B1 = (const float*)d_in[5];
  const float* W2 = (const float*)d_in[6];
  const float* B2 = (const float*)d_in[7];
  float* out = (float*)d_out;

  char* ws = (char*)d_ws;
  u16*   Abuf = (u16*)ws;                                        // 4096x8192 bf16 = 67.1 MB
  u16*   Btbf = (u16*)(ws + (size_t)4096 * 8192 * 2);            // 1024x8192 bf16 = 16.8 MB
  float* P    = (float*)(ws + (size_t)4096 * 8192 * 2
                            + (size_t)1024 * 8192 * 2);          // 2x(4096x1024) / 4x(4096x512) fp32 = 33.6 MB

  // ---- Layer 0: K0=512, EK=4096, N=1024, split-K=2 ----
  expand_a_kernel<<<BATCH * 512 / 8 / 256, 256, 0, stream>>>(x, blend, Abuf, 512);
  convert_w_kernel<<<NE * 1024 * 512 / 8 / 256, 256, 0, stream>>>(W0, Btbf, 1024, 512);
  gemm128_kernel<2><<<dim3(32, 8, 2), 256, 0, stream>>>(Abuf, Btbf, P, 4096, 1024);

  // ---- Layer 1: K0=1024, EK=8192, N=1024, split-K=2 ----
  expand_fused_kernel<<<BATCH * 1024 / 8 / 256, 256, 0, stream>>>(P, blend, B0, Abuf, 1024);
  convert_w_kernel<<<NE * 1024 * 1024 / 8 / 256, 256, 0, stream>>>(W1, Btbf, 1024, 1024);
  gemm128_kernel<2><<<dim3(32, 8, 2), 256, 0, stream>>>(Abuf, Btbf, P, 8192, 1024);

  // ---- Layer 2: K0=1024, EK=8192, N=512, split-K=4, linear ----
  expand_fused_kernel<<<BATCH * 1024 / 8 / 256, 256, 0, stream>>>(P, blend, B1, Abuf, 1024);
  convert_w_kernel<<<NE * 512 * 1024 / 8 / 256, 256, 0, stream>>>(W2, Btbf, 512, 1024);
  gemm128_kernel<4><<<dim3(32, 4, 4), 256, 0, stream>>>(Abuf, Btbf, P, 8192, 512);
  final_combine_kernel<<<BATCH * 512 / 8 / 256, 256, 0, stream>>>(P, blend, B2, out, 512);
}

// Round 3
// 355.422 us; speedup vs baseline: 1.3049x; 1.0591x over previous
//
#include <hip/hip_runtime.h>
#include <cstdint>
#include <cstddef>

typedef __bf16 bf16x8 __attribute__((ext_vector_type(8)));
typedef float f32x4 __attribute__((ext_vector_type(4)));
typedef unsigned short u16;
typedef unsigned short u16x8 __attribute__((ext_vector_type(8)));

#define BATCH 4096
#define NE 8

__device__ __forceinline__ u16 f2bf(float f) {
  union { float f; uint32_t u; } v; v.f = f;
  uint32_t u = v.u;
  u += 0x7fffu + ((u >> 16) & 1u);   // RTNE
  return (u16)(u >> 16);
}

__device__ __forceinline__ void cast8(const float* src, u16* dst) {
  const float4* p = (const float4*)src;
  float4 a = p[0], b = p[1];
  u16x8 o;
  o[0] = f2bf(a.x); o[1] = f2bf(a.y); o[2] = f2bf(a.z); o[3] = f2bf(a.w);
  o[4] = f2bf(b.x); o[5] = f2bf(b.y); o[6] = f2bf(b.z); o[7] = f2bf(b.w);
  *(u16x8*)dst = o;
}

// One dispatch: h0 = bf16(x); W0/W1/W2 (E,N,K0) fp32 -> Bt (N, E*K0) bf16.
__device__ __forceinline__ void conv_w_chunk(const float* __restrict__ W,
                                             u16* __restrict__ Bt,
                                             int N, int K0, int chunk) {
  int per_row = K0 >> 3;
  int rid = chunk / per_row;             // rid = e*N + o
  int i0 = (chunk - rid * per_row) << 3;
  int e = rid / N;
  int o = rid - e * N;
  cast8(W + (size_t)rid * K0 + i0,
        Bt + (size_t)o * ((size_t)NE * K0) + (size_t)e * K0 + i0);
}

__global__ void prep_kernel(const float* __restrict__ x,
                            const float* __restrict__ W0,
                            const float* __restrict__ W1,
                            const float* __restrict__ W2,
                            u16* __restrict__ h0, u16* __restrict__ Bt0,
                            u16* __restrict__ Bt1, u16* __restrict__ Bt2) {
  int t = blockIdx.x * blockDim.x + threadIdx.x;
  const int C0 = BATCH * 512 / 8;            // x cast:   262144
  const int C1 = C0 + NE * 1024 * 512 / 8;   // W0:      +524288
  const int C2 = C1 + NE * 1024 * 1024 / 8;  // W1:      +1048576
  if (t < C0) {
    cast8(x + (size_t)t * 8, h0 + (size_t)t * 8);
  } else if (t < C1) {
    conv_w_chunk(W0, Bt0, 1024, 512, t - C0);
  } else if (t < C2) {
    conv_w_chunk(W1, Bt1, 1024, 1024, t - C1);
  } else {
    conv_w_chunk(W2, Bt2, 512, 1024, t - C2);
  }
}

// Combine SLICES fp32 partials + blended bias; optional ELU; write bf16 h or fp32 out.
template<int SLICES, bool ELU_ACT, bool OUT_BF16>
__global__ void combine_kernel(const float* __restrict__ P,
                               const float* __restrict__ blend,
                               const float* __restrict__ Bias,
                               void* __restrict__ outp, int N) {
  int t = blockIdx.x * blockDim.x + threadIdx.x;
  int per_row = N >> 3;
  int b = t / per_row;
  int i0 = (t - b * per_row) << 3;
  const size_t slice = (size_t)BATCH * N;
  float v[8] = {0, 0, 0, 0, 0, 0, 0, 0};
  #pragma unroll
  for (int s = 0; s < SLICES; ++s) {
    const float4* p = (const float4*)(P + s * slice + (size_t)b * N + i0);
    float4 pa = p[0], pb = p[1];
    v[0] += pa.x; v[1] += pa.y; v[2] += pa.z; v[3] += pa.w;
    v[4] += pb.x; v[5] += pb.y; v[6] += pb.z; v[7] += pb.w;
  }
  const float4* blp = (const float4*)(blend + b * NE);
  float4 u0 = blp[0], u1 = blp[1];
  float bl[8] = {u0.x, u0.y, u0.z, u0.w, u1.x, u1.y, u1.z, u1.w};
  #pragma unroll
  for (int e = 0; e < NE; ++e) {
    const float4* bp = (const float4*)(Bias + (size_t)e * N + i0);
    float4 ba = bp[0], bb = bp[1];
    float bv[8] = {ba.x, ba.y, ba.z, ba.w, bb.x, bb.y, bb.z, bb.w};
    #pragma unroll
    for (int j = 0; j < 8; ++j) v[j] += bl[e] * bv[j];
  }
  if (ELU_ACT) {
    #pragma unroll
    for (int j = 0; j < 8; ++j) v[j] = v[j] > 0.f ? v[j] : expm1f(v[j]);
  }
  if (OUT_BF16) {
    u16x8 o;
    #pragma unroll
    for (int j = 0; j < 8; ++j) o[j] = f2bf(v[j]);
    *(u16x8*)((u16*)outp + (size_t)b * N + i0) = o;
  } else {
    float4* op = (float4*)((float*)outp + (size_t)b * N + i0);
    op[0] = (float4){v[0], v[1], v[2], v[3]};
    op[1] = (float4){v[4], v[5], v[6], v[7]};
  }
}

#define GL2LDS(g, l) __builtin_amdgcn_global_load_lds( \
    (__attribute__((address_space(1))) void*)(g),      \
    (__attribute__((address_space(3))) void*)(l), 16, 0, 0)

// P_z(M x N) = sum_{e in slice z} blend[:,e] * (h @ W_e^T)
// h: (BATCH, K0) bf16 unexpanded. Bt: (N, NE*K0) bf16. Expert-major K loop:
// plain MFMA accumulate over K0 into acc2, then fold acc += blend[row,e]*acc2.
// BM=BN=128, BK=32, 4 waves (2x2), 16 MFMA : 8 ds_read_b128 : 4 glb_load_lds per step.
template<int K0, int NEXP>
__global__ __launch_bounds__(256, 2)
void gemm_hb_kernel(const u16* __restrict__ h, const u16* __restrict__ Bt,
                    const float* __restrict__ blend, float* __restrict__ P, int N) {
  __shared__ __align__(16) u16 Hs[128 * 32];
  __shared__ __align__(16) u16 Bs[128 * 32];
  __shared__ float bls[128 * NE];

  const int tid  = threadIdx.x;
  const int w    = tid >> 6, lane = tid & 63;
  const int wm   = w >> 1,   wn   = w & 1;
  const int lrow = lane & 15, quad = lane >> 4;

  const int row0 = blockIdx.x * 128;
  const int col0 = blockIdx.y * 128;
  const int EK = K0 * NE;
  const int e0 = blockIdx.z * NEXP;

  // stage blend rows for this block (128 x 8 fp32 = 4 KB)
  ((float4*)bls)[tid] = ((const float4*)(blend + (size_t)row0 * NE))[tid];

  const u16* gH0 = h + (size_t)(row0 + (tid >> 2)) * K0 + ((tid & 3) << 3);
  const u16* gH1 = gH0 + (size_t)64 * K0;
  const u16* gB0 = Bt + (size_t)(col0 + (tid >> 2)) * EK + (size_t)e0 * K0 + ((tid & 3) << 3);
  const u16* gB1 = gB0 + (size_t)64 * EK;
  u16* lH0 = &Hs[tid * 8];
  u16* lH1 = &Hs[tid * 8 + 2048];
  u16* lB0 = &Bs[tid * 8];
  u16* lB1 = &Bs[tid * 8 + 2048];

  const u16* fH[4];
  const u16* fB[4];
  #pragma unroll
  for (int i = 0; i < 4; ++i) {
    fH[i] = &Hs[(wm * 64 + i * 16 + lrow) * 32 + quad * 8];
    fB[i] = &Bs[(wn * 64 + i * 16 + lrow) * 32 + quad * 8];
  }

  f32x4 acc[4][4];
  #pragma unroll
  for (int i = 0; i < 4; ++i)
    #pragma unroll
    for (int j = 0; j < 4; ++j) acc[i][j] = (f32x4){0.f, 0.f, 0.f, 0.f};

  #pragma unroll
  for (int e = 0; e < NEXP; ++e) {
    f32x4 acc2[4][4];
    #pragma unroll
    for (int i = 0; i < 4; ++i)
      #pragma unroll
      for (int j = 0; j < 4; ++j) acc2[i][j] = (f32x4){0.f, 0.f, 0.f, 0.f};

    const u16* pH0 = gH0;
    const u16* pH1 = gH1;
    const u16* pB0 = gB0 + (size_t)e * K0;
    const u16* pB1 = gB1 + (size_t)e * K0;

    for (int it = 0; it < K0 / 32; ++it) {
      GL2LDS(pH0, lH0);
      GL2LDS(pH1, lH1);
      GL2LDS(pB0, lB0);
      GL2LDS(pB1, lB1);
      pH0 += 32; pH1 += 32; pB0 += 32; pB1 += 32;
      __syncthreads();

      bf16x8 hf[4], bfr[4];
      #pragma unroll
      for (int i = 0; i < 4; ++i) hf[i] = *(const bf16x8*)fH[i];
      #pragma unroll
      for (int j = 0; j < 4; ++j) bfr[j] = *(const bf16x8*)fB[j];
      #pragma unroll
      for (int i = 0; i < 4; ++i)
        #pragma unroll
        for (int j = 0; j < 4; ++j)
          acc2[i][j] = __builtin_amdgcn_mfma_f32_16x16x32_bf16(hf[i], bfr[j], acc2[i][j], 0, 0, 0);
      __syncthreads();
    }

    // fold: acc += blend[row, e0+e] * acc2   (row = wm*64 + mt*16 + quad*4 + r)
    #pragma unroll
    for (int mt = 0; mt < 4; ++mt) {
      float bl[4];
      #pragma unroll
      for (int r = 0; r < 4; ++r)
        bl[r] = bls[(wm * 64 + mt * 16 + quad * 4 + r) * NE + (e0 + e)];
      #pragma unroll
      for (int nt = 0; nt < 4; ++nt)
        #pragma unroll
        for (int r = 0; r < 4; ++r)
          acc[mt][nt][r] += bl[r] * acc2[mt][nt][r];
    }
  }

  // epilogue: C/D layout col = lane&15, row = quad*4 + reg (m89/m91 verified)
  float* Ps = P + (size_t)blockIdx.z * ((size_t)BATCH * N);
  #pragma unroll
  for (int mt = 0; mt < 4; ++mt) {
    #pragma unroll
    for (int r = 0; r < 4; ++r) {
      int row = row0 + wm * 64 + mt * 16 + quad * 4 + r;
      #pragma unroll
      for (int nt = 0; nt < 4; ++nt) {
        int col = col0 + wn * 64 + nt * 16 + lrow;
        Ps[(size_t)row * N + col] = acc[mt][nt][r];
      }
    }
  }
}

extern "C" void kernel_launch(void* const* d_in, const int* in_sizes, int n_in,
                              void* d_out, int out_size, void* d_ws, size_t ws_size,
                              hipStream_t stream) {
  const float* blend = (const float*)d_in[0];
  const float* x  = (const float*)d_in[1];
  const float* W0 = (const float*)d_in[2];
  const float* B0 = (const float*)d_in[3];
  const float* W1 = (const float*)d_in[4];
  const float* B1 = (const float*)d_in[5];
  const float* W2 = (const float*)d_in[6];
  const float* B2 = (const float*)d_in[7];
  float* out = (float*)d_out;

  char* ws = (char*)d_ws;
  u16*   hA  = (u16*)ws;                           // h0 (4096x512) then h2 (4096x1024); 8.4 MB
  u16*   h1  = (u16*)(ws + 8388608);               // 4096x1024 bf16, 8.4 MB
  u16*   Bt0 = (u16*)(ws + 16777216);              // 1024 x 4096 bf16, 8.4 MB
  u16*   Bt1 = (u16*)(ws + 25165824);              // 1024 x 8192 bf16, 16.8 MB
  u16*   Bt2 = (u16*)(ws + 41943040);              // 512 x 8192 bf16, 8.4 MB
  float* P   = (float*)(ws + 50331648);            // partials, up to 67.1 MB

  // prep: cast x -> h0 and convert all three W to bf16 Bt layout (one dispatch)
  prep_kernel<<<9216, 256, 0, stream>>>(x, W0, W1, W2, hA, Bt0, Bt1, Bt2);

  // Layer 0: K0=512, N=1024, split-K=4 (2 experts/slice), ELU in combine
  gemm_hb_kernel<512, 2><<<dim3(32, 8, 4), 256, 0, stream>>>(hA, Bt0, blend, P, 1024);
  combine_kernel<4, true, true><<<2048, 256, 0, stream>>>(P, blend, B0, h1, 1024);

  // Layer 1: K0=1024, N=1024, split-K=4 (2 experts/slice), ELU in combine
  gemm_hb_kernel<1024, 2><<<dim3(32, 8, 4), 256, 0, stream>>>(h1, Bt1, blend, P, 1024);
  combine_kernel<4, true, true><<<2048, 256, 0, stream>>>(P, blend, B1, hA, 1024);

  // Layer 2: K0=1024, N=512, split-K=8 (1 expert/slice), linear
  gemm_hb_kernel<1024, 1><<<dim3(32, 4, 8), 256, 0, stream>>>(hA, Bt2, blend, P, 512);
  combine_kernel<8, false, false><<<1024, 256, 0, stream>>>(P, blend, B2, out, 512);
}

// Round 4
// 323.157 us; speedup vs baseline: 1.4352x; 1.0998x over previous
//
#include <hip/hip_runtime.h>
#include <cstdint>
#include <cstddef>

typedef __bf16 bf16x8 __attribute__((ext_vector_type(8)));
typedef float f32x4 __attribute__((ext_vector_type(4)));
typedef unsigned short u16;
typedef unsigned short u16x8 __attribute__((ext_vector_type(8)));

#define BATCH 4096
#define NE 8

__device__ __forceinline__ u16 f2bf(float f) {
  union { float f; uint32_t u; } v; v.f = f;
  uint32_t u = v.u;
  u += 0x7fffu + ((u >> 16) & 1u);   // RTNE
  return (u16)(u >> 16);
}

__device__ __forceinline__ float bf2f(u16 u) {
  union { uint32_t u; float f; } v; v.u = ((uint32_t)u) << 16;
  return v.f;
}

__device__ __forceinline__ void cast8(const float* src, u16* dst) {
  const float4* p = (const float4*)src;
  float4 a = p[0], b = p[1];
  u16x8 o;
  o[0] = f2bf(a.x); o[1] = f2bf(a.y); o[2] = f2bf(a.z); o[3] = f2bf(a.w);
  o[4] = f2bf(b.x); o[5] = f2bf(b.y); o[6] = f2bf(b.z); o[7] = f2bf(b.w);
  *(u16x8*)dst = o;
}

// One dispatch: h0 = bf16(x); W0/W1/W2 (E,N,K0) fp32 -> Bt (N, E*K0) bf16.
__device__ __forceinline__ void conv_w_chunk(const float* __restrict__ W,
                                             u16* __restrict__ Bt,
                                             int N, int K0, int chunk) {
  int per_row = K0 >> 3;
  int rid = chunk / per_row;             // rid = e*N + o
  int i0 = (chunk - rid * per_row) << 3;
  int e = rid / N;
  int o = rid - e * N;
  cast8(W + (size_t)rid * K0 + i0,
        Bt + (size_t)o * ((size_t)NE * K0) + (size_t)e * K0 + i0);
}

__global__ void prep_kernel(const float* __restrict__ x,
                            const float* __restrict__ W0,
                            const float* __restrict__ W1,
                            const float* __restrict__ W2,
                            u16* __restrict__ h0, u16* __restrict__ Bt0,
                            u16* __restrict__ Bt1, u16* __restrict__ Bt2) {
  int t = blockIdx.x * blockDim.x + threadIdx.x;
  const int C0 = BATCH * 512 / 8;            // x cast:   262144
  const int C1 = C0 + NE * 1024 * 512 / 8;   // W0:      +524288
  const int C2 = C1 + NE * 1024 * 1024 / 8;  // W1:      +1048576
  if (t < C0) {
    cast8(x + (size_t)t * 8, h0 + (size_t)t * 8);
  } else if (t < C1) {
    conv_w_chunk(W0, Bt0, 1024, 512, t - C0);
  } else if (t < C2) {
    conv_w_chunk(W1, Bt1, 1024, 1024, t - C1);
  } else {
    conv_w_chunk(W2, Bt2, 512, 1024, t - C2);
  }
}

// out[b,o] = sum_e blend[b,e]*(P_e[b,o] + Bias[e,o]); optional ELU; bf16 or fp32 out.
template<bool ELU_ACT, bool OUT_BF16>
__global__ void combine8_kernel(const u16* __restrict__ P,
                                const float* __restrict__ blend,
                                const float* __restrict__ Bias,
                                void* __restrict__ outp, int N) {
  int t = blockIdx.x * blockDim.x + threadIdx.x;
  int per_row = N >> 3;
  int b = t / per_row;
  int i0 = (t - b * per_row) << 3;
  const size_t slice = (size_t)BATCH * N;
  const float4* blp = (const float4*)(blend + b * NE);
  float4 u0 = blp[0], u1 = blp[1];
  float bl[8] = {u0.x, u0.y, u0.z, u0.w, u1.x, u1.y, u1.z, u1.w};
  float v[8] = {0, 0, 0, 0, 0, 0, 0, 0};
  #pragma unroll
  for (int e = 0; e < NE; ++e) {
    u16x8 pv = *(const u16x8*)(P + (size_t)e * slice + (size_t)b * N + i0);
    #pragma unroll
    for (int j = 0; j < 8; ++j) v[j] += bl[e] * bf2f(pv[j]);
  }
  #pragma unroll
  for (int e = 0; e < NE; ++e) {
    const float4* bp = (const float4*)(Bias + (size_t)e * N + i0);
    float4 ba = bp[0], bb = bp[1];
    float bv[8] = {ba.x, ba.y, ba.z, ba.w, bb.x, bb.y, bb.z, bb.w};
    #pragma unroll
    for (int j = 0; j < 8; ++j) v[j] += bl[e] * bv[j];
  }
  if (ELU_ACT) {
    #pragma unroll
    for (int j = 0; j < 8; ++j) v[j] = v[j] > 0.f ? v[j] : expm1f(v[j]);
  }
  if (OUT_BF16) {
    u16x8 o;
    #pragma unroll
    for (int j = 0; j < 8; ++j) o[j] = f2bf(v[j]);
    *(u16x8*)((u16*)outp + (size_t)b * N + i0) = o;
  } else {
    float4* op = (float4*)((float*)outp + (size_t)b * N + i0);
    op[0] = (float4){v[0], v[1], v[2], v[3]};
    op[1] = (float4){v[4], v[5], v[6], v[7]};
  }
}

#define GL2LDS(g, l) __builtin_amdgcn_global_load_lds( \
    (__attribute__((address_space(1))) void*)(g),      \
    (__attribute__((address_space(3))) void*)(l), 16, 0, 0)

// Batched-expert GEMM: P_e(M x N) = h(M x K0) @ W_e(N x K0)^T, bf16 partials.
// blockIdx.z = expert. m97 structure: BM=BN=128, BK=32, 4 waves (2x2),
// 16 MFMA : 8 ds_read_b128 : 4 global_load_lds per K-step. acc only (64 AGPR).
template<int K0>
__global__ __launch_bounds__(256, 4)
void gemm_be_kernel(const u16* __restrict__ h, const u16* __restrict__ Bt,
                    u16* __restrict__ P, int N) {
  __shared__ __align__(16) u16 Hs[128 * 32];
  __shared__ __align__(16) u16 Bs[128 * 32];

  const int tid  = threadIdx.x;
  const int w    = tid >> 6, lane = tid & 63;
  const int wm   = w >> 1,   wn   = w & 1;
  const int lrow = lane & 15, quad = lane >> 4;

  const int row0 = blockIdx.x * 128;
  const int col0 = blockIdx.y * 128;
  const int e    = blockIdx.z;
  const int EK   = K0 * NE;

  const u16* gH0 = h + (size_t)(row0 + (tid >> 2)) * K0 + ((tid & 3) << 3);
  const u16* gH1 = gH0 + (size_t)64 * K0;
  const u16* gB0 = Bt + (size_t)(col0 + (tid >> 2)) * EK + (size_t)e * K0 + ((tid & 3) << 3);
  const u16* gB1 = gB0 + (size_t)64 * EK;
  u16* lH0 = &Hs[tid * 8];
  u16* lH1 = &Hs[tid * 8 + 2048];
  u16* lB0 = &Bs[tid * 8];
  u16* lB1 = &Bs[tid * 8 + 2048];

  const u16* fH[4];
  const u16* fB[4];
  #pragma unroll
  for (int i = 0; i < 4; ++i) {
    fH[i] = &Hs[(wm * 64 + i * 16 + lrow) * 32 + quad * 8];
    fB[i] = &Bs[(wn * 64 + i * 16 + lrow) * 32 + quad * 8];
  }

  f32x4 acc[4][4];
  #pragma unroll
  for (int i = 0; i < 4; ++i)
    #pragma unroll
    for (int j = 0; j < 4; ++j) acc[i][j] = (f32x4){0.f, 0.f, 0.f, 0.f};

  for (int it = 0; it < K0 / 32; ++it) {
    GL2LDS(gH0, lH0);
    GL2LDS(gH1, lH1);
    GL2LDS(gB0, lB0);
    GL2LDS(gB1, lB1);
    gH0 += 32; gH1 += 32; gB0 += 32; gB1 += 32;
    __syncthreads();

    bf16x8 hf[4], bfr[4];
    #pragma unroll
    for (int i = 0; i < 4; ++i) hf[i] = *(const bf16x8*)fH[i];
    #pragma unroll
    for (int j = 0; j < 4; ++j) bfr[j] = *(const bf16x8*)fB[j];
    #pragma unroll
    for (int i = 0; i < 4; ++i)
      #pragma unroll
      for (int j = 0; j < 4; ++j)
        acc[i][j] = __builtin_amdgcn_mfma_f32_16x16x32_bf16(hf[i], bfr[j], acc[i][j], 0, 0, 0);
    __syncthreads();
  }

  // epilogue: C/D layout col = lane&15, row = quad*4 + reg (m89/m91 verified)
  u16* Ps = P + (size_t)e * ((size_t)BATCH * N);
  #pragma unroll
  for (int mt = 0; mt < 4; ++mt) {
    #pragma unroll
    for (int r = 0; r < 4; ++r) {
      int row = row0 + wm * 64 + mt * 16 + quad * 4 + r;
      #pragma unroll
      for (int nt = 0; nt < 4; ++nt) {
        int col = col0 + wn * 64 + nt * 16 + lrow;
        Ps[(size_t)row * N + col] = f2bf(acc[mt][nt][r]);
      }
    }
  }
}

extern "C" void kernel_launch(void* const* d_in, const int* in_sizes, int n_in,
                              void* d_out, int out_size, void* d_ws, size_t ws_size,
                              hipStream_t stream) {
  const float* blend = (const float*)d_in[0];
  const float* x  = (const float*)d_in[1];
  const float* W0 = (const float*)d_in[2];
  const float* B0 = (const float*)d_in[3];
  const float* W1 = (const float*)d_in[4];
  const float* B1 = (const float*)d_in[5];
  const float* W2 = (const float*)d_in[6];
  const float* B2 = (const float*)d_in[7];
  float* out = (float*)d_out;

  char* ws = (char*)d_ws;
  u16* hA  = (u16*)ws;                           // h0 (4096x512) then h2 (4096x1024); 8.4 MB
  u16* h1  = (u16*)(ws + 8388608);               // 4096x1024 bf16, 8.4 MB
  u16* Bt0 = (u16*)(ws + 16777216);              // 1024 x 4096 bf16, 8.4 MB
  u16* Bt1 = (u16*)(ws + 25165824);              // 1024 x 8192 bf16, 16.8 MB
  u16* Bt2 = (u16*)(ws + 41943040);              // 512 x 8192 bf16, 8.4 MB
  u16* P   = (u16*)(ws + 50331648);              // bf16 partials, 8 x 4096 x 1024 = 67.1 MB

  // prep: cast x -> h0 and convert all three W to bf16 Bt layout (one dispatch)
  prep_kernel<<<9216, 256, 0, stream>>>(x, W0, W1, W2, hA, Bt0, Bt1, Bt2);

  // Layer 0: K0=512, N=1024; 8 expert slices; blend+bias+ELU in combine
  gemm_be_kernel<512><<<dim3(32, 8, 8), 256, 0, stream>>>(hA, Bt0, P, 1024);
  combine8_kernel<true, true><<<2048, 256, 0, stream>>>(P, blend, B0, h1, 1024);

  // Layer 1: K0=1024, N=1024
  gemm_be_kernel<1024><<<dim3(32, 8, 8), 256, 0, stream>>>(h1, Bt1, P, 1024);
  combine8_kernel<true, true><<<2048, 256, 0, stream>>>(P, blend, B1, hA, 1024);

  // Layer 2: K0=1024, N=512, linear, fp32 out
  gemm_be_kernel<1024><<<dim3(32, 4, 8), 256, 0, stream>>>(hA, Bt2, P, 512);
  combine8_kernel<false, false><<<1024, 256, 0, stream>>>(P, blend, B2, out, 512);
}